// Round 15
// baseline (4420.248 us; speedup 1.0000x reference)
//
#include <hip/hip_runtime.h>

#define NIN  512
#define NREC 2048
#define NOUT 128
#define BB   64
#define TT   250

// OUTPUTS ARE FLOAT32 (R9 probe). Semantics: JAX text (R10 PASS, absmax 0.0078125).
// R28: R27 base (tied-best 3718us) + two bit-exact micro-opts:
//  (1) FMA-select ACCEV: a += fma(wd, dd==k ? 1.0 : 0.0, a). 1.0/0.0 share a
//      zero low word -> single cndmask_b32 + v_fma_f64 per slot (was cmp +
//      2 cndmask + add). fma(w,1,a)=round(w+a)=add; fma(w,0,a)=a (+0 safe:
//      ring slots never -0). ~20% off scatter VALU.
//  (2) Ballot pipelining: step t's tail runs the input ballot/scan for t+1;
//      B6(combine) doubles as icnt barrier, B5(publish) as ilist barrier ->
//      4 barriers/step (was 6). itot carried in-register; t=0 ballot in
//      prologue. ilist read(t) / write(t+1) separated by B6 at every t.
// R27: unroll-16 scatter (neutral, kept). R24: RELAXED spin (acquire's
//      per-poll buffer_inv nuked XCD L2; +7.5%). R17/R18: 256x1024, 2
//      threads/neuron, halves split lists, f64 partials combined via LDS.
//      R15 gate: z_{t-1} delivered iff t>=2. ACC order ascending -> bit-exact.
// ---- d_ws layout (~28.3 MB; 34.5 MB verified safe) ----
#define OFF_WRT  0UL          // f32 W_rT [n][m] (exact; 0 where d==0) 16,777,216
#define OFF_DP2  16777216UL   // u32 dP2[n][m/16] 2-bit delays         1,048,576
#define OFF_WIT  17825792UL   // f32 W_i^T [i][m]                      4,194,304
#define OFF_WOT  22020096UL   // f32 W_o^T [n][o]                      1,048,576
#define OFF_MASK 23068672UL   // u32 masks [t*64+b][64]                4,096,000
#define OFF_G    27164672UL   // f64 g[b][n]                           1,048,576
#define OFF_CNT  28213248UL   // u32 cnt[t*64+b]                          64,000

__device__ __forceinline__ int decode_delay(int v) {
    if (v >= 0 && v <= 4) return v;
    const float f = __int_as_float(v);
    if (f >= 0.5f && f <= 4.5f) return (int)(f + 0.5f);
    return 0;
}
__device__ __forceinline__ int delay_like(int v) {
    if (v >= 0 && v <= 4) return 1;
    const float f = __int_as_float(v);
    return (f >= 0.5f && f <= 4.5f) ? 1 : 0;
}
__device__ __forceinline__ unsigned lane_rank(unsigned long long m) {
    unsigned r = __builtin_amdgcn_mbcnt_lo((unsigned)m, 0u);
    return __builtin_amdgcn_mbcnt_hi((unsigned)(m >> 32), r);
}

__global__ __launch_bounds__(256) void k_prep(
    const void* __restrict__ c4A, const void* __restrict__ c4B,
    const float* __restrict__ Wi, const float* __restrict__ Wo,
    float* __restrict__ WrT, unsigned* __restrict__ dP2,
    float* __restrict__ WiT, float* __restrict__ WoT)
{
    const int* iA = (const int*)c4A;
    const int* iB = (const int*)c4B;
    int cntA = 0, cntB = 0;
    for (int j = 0; j < 64; ++j) { cntA += delay_like(iA[j]); cntB += delay_like(iB[j]); }
    const int*   dl = (cntA >= cntB) ? iA : iB;
    const float* Wr = (cntA >= cntB) ? (const float*)c4B : (const float*)c4A;

    const int idx = blockIdx.x * 256 + threadIdx.x;
    if (idx < NREC * NREC) {
        const int n = idx >> 11, m = idx & 2047;
        const int d = decode_delay(dl[idx]);
        const float w = Wr[(size_t)m * NREC + n];        // W_rT[n][m] = W_r[m][n]
        WrT[idx] = (d == 0) ? 0.0f : w;                  // exact bits where it matters
        if ((m & 15) == 0) {                             // pack 16 delays -> 1 u32
            unsigned pw = 0;
            for (int j = 0; j < 16; ++j) {
                const int dj = decode_delay(dl[idx + j]);
                const unsigned e = (dj == 0) ? 0u : (unsigned)(dj - 1);
                pw |= e << (2 * j);
            }
            dP2[idx >> 4] = pw;
        }
    }
    if (idx < NIN * NREC) {
        const int i = idx >> 11, m = idx & 2047;
        WiT[idx] = Wi[(size_t)m * NIN + i];              // W_iT[i][m]
    }
    if (idx < NREC * NOUT) {
        const int n = idx >> 7, o = idx & 127;
        WoT[idx] = Wo[(size_t)o * NREC + n];             // W_oT[n][o]
    }
}

// per-event accumulate via FMA-select (R28): fma(wd, sel01, a) with sel01 in
// {1.0, 0.0} sharing a zero low word -> 1 cndmask_b32 + 1 v_fma_f64 per slot.
// Bit-exact vs add: fma(w,1,a)=round(w+a); fma(w,0,a)=a (+0-safe).
#define ACCEV(wf, ee) { const int dd = (int)(((ee) >> sh) & 3u);                \
    const double wd = (double)(wf);                                             \
    a0 = __builtin_fma(wd, (dd == 0) ? 1.0 : 0.0, a0);                          \
    a1 = __builtin_fma(wd, (dd == 1) ? 1.0 : 0.0, a1);                          \
    a2 = __builtin_fma(wd, (dd == 2) ? 1.0 : 0.0, a2);                          \
    a3 = __builtin_fma(wd, (dd == 3) ? 1.0 : 0.0, a3); }

// 256 blocks x 1024 threads. Block (b,q) owns neuron cols [512q,512q+512) of
// batch b; 2 threads/neuron (half=tid>>9). Per-step phase order (R28):
//   gather from ilist (built last step) -> relaxed spin cnt[t-1]==4 -> B3 ->
//   wave0: masks+scan+slist -> B4 -> split scatter (t>=2, unroll-16) ->
//   [tail: ballot(t+1) + combine stores] -> B6 -> LIF + scan/ilist(t+1) +
//   ring rotate -> publish z_t -> B5 -> release cnt[t].
// Residency: 16 waves/block; all 256 blocks co-resident -> spin can't deadlock.
__global__ __launch_bounds__(1024) void k_main(
    const float* __restrict__ x,
    const float* __restrict__ WrT,
    const unsigned* __restrict__ dP2,
    const float* __restrict__ WiT,
    const float* __restrict__ Br,
    const float* __restrict__ tau_rec, const float* __restrict__ tau_out,
    const float* __restrict__ thr_rec,
    unsigned* __restrict__ spikeMask, unsigned* __restrict__ cnt,
    double* __restrict__ g)
{
    __shared__ int icnt[8];
    __shared__ __align__(16) unsigned short ilist[NIN];
    __shared__ __align__(16) unsigned short slist[NREC];
    __shared__ int stot_s;
    __shared__ double aEx[512];
    __shared__ double cEx[512];

    const int gid = blockIdx.x;
    const int r8  = gid & 7, kk0 = gid >> 3;
    const int q   = r8 >> 1;
    const int b   = kk0 * 2 + (r8 & 1);
    const int tid  = threadIdx.x;
    const int half = tid >> 9;               // 0: front events + LIF; 1: back events
    const int u    = tid & 511;              // neuron index within block slice
    const int w    = tid >> 6;               // wave 0..15
    const int lane = tid & 63;
    const int col  = q * 512 + u;            // my neuron (global id)
    const unsigned colu = (unsigned)col;
    const unsigned c4i  = colu >> 4;         // dP2 word column (per-thread const)
    const int sh        = (col & 15) * 2;    // dP2 bit shift   (per-thread const)

    const double rec_c = exp(-0.01 / (double)tau_rec[0]);
    const double out_c = exp(-0.01 / (double)tau_out[0]);
    const double thr   = (double)thr_rec[0];
    const double br    = (double)Br[col];
    double mem = 0.0, gacc = 0.0;
    double a0 = 0.0, a1 = 0.0, a2 = 0.0, a3 = 0.0;   // per-half register delay ring

    const float* xb = x + (size_t)b * NIN * TT;      // x[b][i][t]
    const float* Wc = WiT + col;                     // per-thread input column base

    // ---- prologue: ballot+list for t=0 ----
    float xv = (half == 0) ? xb[(size_t)u * TT] : 0.f;   // u < 512 == NIN
    int itot;
    {
        const bool ihit = (xv != 0.f);
        const unsigned long long im = __ballot(ihit);
        if (w < 8 && lane == 0) icnt[w] = __popcll(im);
        __syncthreads();
        int ioffw = 0; itot = 0;
#pragma unroll
        for (int j = 0; j < 8; ++j) { const int c = icnt[j]; if (j < w) ioffw += c; itot += c; }
        if (ihit) ilist[ioffw + lane_rank(im)] = (unsigned short)u;
        __syncthreads();
    }
    xv = (half == 0) ? xb[(size_t)u * TT + 1] : 0.f;     // preload t=1 value

    for (int t = 0; t < TT; ++t) {
        // ---- split input gather for step t (list built last step) ----
        int iHalf = ((itot >> 1) + 7) & ~7; if (iHalf > itot) iHalf = itot;  // 8-aligned split
        const int ikb = half ? iHalf : 0;
        const int ike = half ? itot  : iHalf;
        double cin = 0.0;
        {
            int k = ikb;
            for (; k + 8 <= ike; k += 8) {
                const uint4 sv = *reinterpret_cast<const uint4*>(&ilist[k]);
                const float v0 = Wc[(sv.x & 0xffffu) << 11];
                const float v1 = Wc[(sv.x >> 16)     << 11];
                const float v2 = Wc[(sv.y & 0xffffu) << 11];
                const float v3 = Wc[(sv.y >> 16)     << 11];
                const float v4 = Wc[(sv.z & 0xffffu) << 11];
                const float v5 = Wc[(sv.z >> 16)     << 11];
                const float v6 = Wc[(sv.w & 0xffffu) << 11];
                const float v7 = Wc[(sv.w >> 16)     << 11];
                cin += (double)v0; cin += (double)v1; cin += (double)v2; cin += (double)v3;
                cin += (double)v4; cin += (double)v5; cin += (double)v6; cin += (double)v7;
            }
            for (; k < ike; ++k) cin += (double)Wc[(unsigned)ilist[k] << 11];
        }

        // ---- wait for siblings' z_{t-1}; deliver only if t-1 > 0 (R15 gate) ----
        if (t >= 2) {
            const unsigned* gmp = spikeMask + (size_t)((t - 1) * BB + b) * 64;
            if (tid == 0) {
                // RELAXED poll (R24): acquire's per-poll buffer_inv would nuke
                // the XCD L2 weight slice. Ordering: producers drain sc1 mask
                // stores at their B5 before the release-add; our reads are
                // relaxed sc1 loads after the spin + B3.
                while (__hip_atomic_load(&cnt[(t - 1) * BB + b],
                                         __ATOMIC_RELAXED, __HIP_MEMORY_SCOPE_AGENT) < 4u)
                    __builtin_amdgcn_s_sleep(1);
            }
            __syncthreads();                           // B3: z_{t-1} all published
            if (tid < 64) {                            // wave 0: scan + emit slist
                const unsigned wv = __hip_atomic_load(&gmp[tid],
                                        __ATOMIC_RELAXED, __HIP_MEMORY_SCOPE_AGENT);
                const int zc = __popc(wv);
                int inc = zc;
#pragma unroll
                for (int s = 1; s < 64; s <<= 1) {
                    const int up = __shfl_up(inc, s, 64);
                    if (lane >= s) inc += up;
                }
                int off = inc - zc;                    // exclusive prefix
                if (lane == 63) stot_s = inc;
                unsigned bits = wv;
                while (bits) {
                    const int bp = __ffs(bits) - 1;
                    bits &= bits - 1;
                    slist[off++] = (unsigned short)(tid * 32 + bp);
                }
            }
            __syncthreads();                           // B4: slist/stot ready
            const int stot = stot_s;
            int sHalf = ((stot >> 1) + 7) & ~7; if (sHalf > stot) sHalf = stot; // 8-aligned
            const int kb = half ? sHalf : 0;
            const int ke = half ? stot  : sHalf;
            int k = kb;
            // ---- unroll-16 scatter: 32 loads per straight-line block ----
            for (; k + 16 <= ke; k += 16) {
                const uint4 sa = *reinterpret_cast<const uint4*>(&slist[k]);
                const uint4 sb = *reinterpret_cast<const uint4*>(&slist[k + 8]);
                const unsigned n0 = sa.x & 0xffffu, n1 = sa.x >> 16;
                const unsigned n2 = sa.y & 0xffffu, n3 = sa.y >> 16;
                const unsigned n4 = sa.z & 0xffffu, n5 = sa.z >> 16;
                const unsigned n6 = sa.w & 0xffffu, n7 = sa.w >> 16;
                const unsigned n8 = sb.x & 0xffffu, n9 = sb.x >> 16;
                const unsigned nA = sb.y & 0xffffu, nB = sb.y >> 16;
                const unsigned nC = sb.z & 0xffffu, nD = sb.z >> 16;
                const unsigned nE = sb.w & 0xffffu, nF = sb.w >> 16;
                const float w0 = WrT[(n0 << 11) | colu]; const unsigned e0 = dP2[(n0 << 7) | c4i];
                const float w1 = WrT[(n1 << 11) | colu]; const unsigned e1 = dP2[(n1 << 7) | c4i];
                const float w2 = WrT[(n2 << 11) | colu]; const unsigned e2 = dP2[(n2 << 7) | c4i];
                const float w3 = WrT[(n3 << 11) | colu]; const unsigned e3 = dP2[(n3 << 7) | c4i];
                const float w4 = WrT[(n4 << 11) | colu]; const unsigned e4 = dP2[(n4 << 7) | c4i];
                const float w5 = WrT[(n5 << 11) | colu]; const unsigned e5 = dP2[(n5 << 7) | c4i];
                const float w6 = WrT[(n6 << 11) | colu]; const unsigned e6 = dP2[(n6 << 7) | c4i];
                const float w7 = WrT[(n7 << 11) | colu]; const unsigned e7 = dP2[(n7 << 7) | c4i];
                const float w8 = WrT[(n8 << 11) | colu]; const unsigned e8 = dP2[(n8 << 7) | c4i];
                const float w9 = WrT[(n9 << 11) | colu]; const unsigned e9 = dP2[(n9 << 7) | c4i];
                const float wA = WrT[(nA << 11) | colu]; const unsigned eA = dP2[(nA << 7) | c4i];
                const float wB = WrT[(nB << 11) | colu]; const unsigned eB = dP2[(nB << 7) | c4i];
                const float wC = WrT[(nC << 11) | colu]; const unsigned eC = dP2[(nC << 7) | c4i];
                const float wD = WrT[(nD << 11) | colu]; const unsigned eD = dP2[(nD << 7) | c4i];
                const float wE = WrT[(nE << 11) | colu]; const unsigned eE = dP2[(nE << 7) | c4i];
                const float wF = WrT[(nF << 11) | colu]; const unsigned eF = dP2[(nF << 7) | c4i];
                ACCEV(w0, e0) ACCEV(w1, e1) ACCEV(w2, e2) ACCEV(w3, e3)
                ACCEV(w4, e4) ACCEV(w5, e5) ACCEV(w6, e6) ACCEV(w7, e7)
                ACCEV(w8, e8) ACCEV(w9, e9) ACCEV(wA, eA) ACCEV(wB, eB)
                ACCEV(wC, eC) ACCEV(wD, eD) ACCEV(wE, eE) ACCEV(wF, eF)
            }
            for (; k + 8 <= ke; k += 8) {
                const uint4 sv = *reinterpret_cast<const uint4*>(&slist[k]);
                const unsigned n0 = sv.x & 0xffffu, n1 = sv.x >> 16;
                const unsigned n2 = sv.y & 0xffffu, n3 = sv.y >> 16;
                const unsigned n4 = sv.z & 0xffffu, n5 = sv.z >> 16;
                const unsigned n6 = sv.w & 0xffffu, n7 = sv.w >> 16;
                const float w0 = WrT[(n0 << 11) | colu]; const unsigned e0 = dP2[(n0 << 7) | c4i];
                const float w1 = WrT[(n1 << 11) | colu]; const unsigned e1 = dP2[(n1 << 7) | c4i];
                const float w2 = WrT[(n2 << 11) | colu]; const unsigned e2 = dP2[(n2 << 7) | c4i];
                const float w3 = WrT[(n3 << 11) | colu]; const unsigned e3 = dP2[(n3 << 7) | c4i];
                const float w4 = WrT[(n4 << 11) | colu]; const unsigned e4 = dP2[(n4 << 7) | c4i];
                const float w5 = WrT[(n5 << 11) | colu]; const unsigned e5 = dP2[(n5 << 7) | c4i];
                const float w6 = WrT[(n6 << 11) | colu]; const unsigned e6 = dP2[(n6 << 7) | c4i];
                const float w7 = WrT[(n7 << 11) | colu]; const unsigned e7 = dP2[(n7 << 7) | c4i];
                ACCEV(w0, e0) ACCEV(w1, e1) ACCEV(w2, e2) ACCEV(w3, e3)
                ACCEV(w4, e4) ACCEV(w5, e5) ACCEV(w6, e6) ACCEV(w7, e7)
            }
            for (; k < ke; ++k) {
                const unsigned n0 = (unsigned)slist[k];
                const float w0 = WrT[(n0 << 11) | colu];
                const unsigned e0 = dP2[(n0 << 7) | c4i];
                ACCEV(w0, e0)
            }
        }

        // ---- tail: ballot for t+1 (xv holds x[t+1]) + combine stores ----
        const bool ihit2 = (xv != 0.f);
        const unsigned long long im2 = __ballot(ihit2);
        if (w < 8 && lane == 0) icnt[w] = __popcll(im2);
        float xvn = 0.f;
        if (half == 0 && t + 2 < TT) xvn = xb[(size_t)u * TT + (t + 2)];
        if (half) { aEx[u] = a0; cEx[u] = cin; }
        __syncthreads();                               // B6: partials + icnt ready

        bool z = false;
        if (half == 0) {
            const double cur = (a0 + aEx[u]) + (cin + cEx[u]) + br;
            mem = mem * rec_c + cur;
            z = (mem - thr) > 0.0;
            if (z) mem -= thr;
            gacc = gacc * out_c + (z ? 1.0 : 0.0);
        }
        // scan + write ilist for t+1 (reads of ilist for t were before B6)
        int ioffw2 = 0, itot2 = 0;
#pragma unroll
        for (int j = 0; j < 8; ++j) { const int c = icnt[j]; if (j < w) ioffw2 += c; itot2 += c; }
        if (ihit2) ilist[ioffw2 + lane_rank(im2)] = (unsigned short)u;
        a0 = a1; a1 = a2; a2 = a3; a3 = 0.0;           // both halves rotate

        // ---- publish z_t from half0 wave ballots ----
        const unsigned long long mz = __ballot(z);
        unsigned* gm = spikeMask + (size_t)(t * BB + b) * 64;
        if (w < 8) {
            if (lane == 0)
                __hip_atomic_store(&gm[q * 16 + 2 * w], (unsigned)(mz & 0xFFFFFFFFu),
                                   __ATOMIC_RELAXED, __HIP_MEMORY_SCOPE_AGENT);
            if (lane == 32)
                __hip_atomic_store(&gm[q * 16 + 2 * w + 1], (unsigned)(mz >> 32),
                                   __ATOMIC_RELAXED, __HIP_MEMORY_SCOPE_AGENT);
        }
        __syncthreads();                               // B5: stores drained + ilist ready
        if (tid == 0)
            __hip_atomic_fetch_add(&cnt[t * BB + b], 1u,
                                   __ATOMIC_RELEASE, __HIP_MEMORY_SCOPE_AGENT);
        itot = itot2;
        xv = xvn;
    }

    if (half == 0) g[(size_t)b * NREC + col] = gacc;
}

__global__ __launch_bounds__(256) void k_memout(
    const double* __restrict__ g, const float* __restrict__ WoT,
    const float* __restrict__ Bo, const float* __restrict__ tau_out,
    float* __restrict__ mout)
{
    __shared__ double gs[NREC];
    const int b = blockIdx.x, tid = threadIdx.x;
#pragma unroll
    for (int k = 0; k < 8; ++k)
        gs[tid + 256 * k] = g[(size_t)b * NREC + tid + 256 * k];
    const double c = exp(-0.01 / (double)tau_out[0]);
    double S = 0.0;
    for (int t = 0; t < TT; ++t) S = S * c + 1.0;
    __syncthreads();
    if (tid < NOUT) {
        double a = 0.0;
        for (int n = 0; n < NREC; ++n)
            a += gs[n] * (double)WoT[n * NOUT + tid];
        a += (double)Bo[tid] * S;
        mout[(size_t)b * NOUT + tid] = (float)a;
    }
}

__global__ __launch_bounds__(256) void k_expand(
    const unsigned* __restrict__ spikeMask, float* __restrict__ zout)
{
    const int bid = blockIdx.x;
    const int b = bid >> 6, gw = bid & 63;
    const int t = threadIdx.x;
    if (t >= TT) return;
    const unsigned v = spikeMask[((size_t)(t * BB + b)) * 64 + gw];
    for (int j = 0; j < 32; ++j) {
        const int n = gw * 32 + j;
        zout[((size_t)b * NREC + n) * TT + t] = ((v >> j) & 1u) ? 1.0f : 0.0f;
    }
}

extern "C" void kernel_launch(void* const* d_in, const int* in_sizes, int n_in,
                              void* d_out, int out_size, void* d_ws, size_t ws_size,
                              hipStream_t stream) {
    const float *x = nullptr, *Wi = nullptr, *Wo = nullptr, *Br = nullptr, *Bo = nullptr;
    const void* c4[2] = {nullptr, nullptr};
    const float* sc[3] = {nullptr, nullptr, nullptr};
    int n4 = 0, nsc = 0;
    for (int i = 0; i < n_in; ++i) {
        switch (in_sizes[i]) {
            case 8192000: x  = (const float*)d_in[i]; break;
            case 1048576: Wi = (const float*)d_in[i]; break;
            case 262144:  Wo = (const float*)d_in[i]; break;
            case 2048:    Br = (const float*)d_in[i]; break;
            case 128:     Bo = (const float*)d_in[i]; break;
            case 4194304: if (n4 < 2)  c4[n4++]  = d_in[i]; break;
            case 1:       if (nsc < 3) sc[nsc++] = (const float*)d_in[i]; break;
            default: break;
        }
    }
    if (!x || !Wi || !Wo || !Br || !Bo || n4 < 2 || nsc < 3) {
        x  = (const float*)d_in[0];
        c4[0] = d_in[1];
        Wi = (const float*)d_in[2];
        c4[1] = d_in[3];
        Wo = (const float*)d_in[4];
        Br = (const float*)d_in[5];
        Bo = (const float*)d_in[6];
        sc[0] = (const float*)d_in[7];
        sc[1] = (const float*)d_in[8];
        sc[2] = (const float*)d_in[9];
    }
    const float* taur = sc[0];
    const float* tauo = sc[1];
    const float* thr  = sc[2];

    float* out = (float*)d_out;
    char* ws = (char*)d_ws;
    float*          WrT  = (float*)(ws + OFF_WRT);
    unsigned*       dP2  = (unsigned*)(ws + OFF_DP2);
    float*          WiT  = (float*)(ws + OFF_WIT);
    float*          WoT  = (float*)(ws + OFF_WOT);
    unsigned*       mask = (unsigned*)(ws + OFF_MASK);
    double*         g    = (double*)(ws + OFF_G);
    unsigned*       cnt  = (unsigned*)(ws + OFF_CNT);

    hipMemsetAsync(cnt, 0, (size_t)TT * BB * sizeof(unsigned), stream);
    hipLaunchKernelGGL(k_prep, dim3((NREC * NREC + 255) / 256), dim3(256), 0, stream,
                       c4[0], c4[1], Wi, Wo, WrT, dP2, WiT, WoT);
    hipLaunchKernelGGL(k_main, dim3(256), dim3(1024), 0, stream,
                       x, WrT, dP2, WiT, Br, taur, tauo, thr, mask, cnt, g);
    hipLaunchKernelGGL(k_memout, dim3(BB), dim3(256), 0, stream,
                       g, WoT, Bo, tauo, out);
    hipLaunchKernelGGL(k_expand, dim3(BB * 64), dim3(256), 0, stream,
                       mask, out + 8192);
}

// Round 16
// 3836.719 us; speedup vs baseline: 1.1521x; 1.1521x over previous
//
#include <hip/hip_runtime.h>

#define NIN  512
#define NREC 2048
#define NOUT 128
#define BB   64
#define TT   250

// OUTPUTS ARE FLOAT32 (R9 probe). Semantics: JAX text (R10 PASS, absmax 0.0078125).
// R29: R24 base (best verified, 3695us) + ONE change: FMA-select ACCEV.
//      R28 bundled FMA-select + ballot-pipelining and regressed 12%; the
//      pipelining moved the icnt/ilist scan into the B6->B5 publish window =
//      the global rendezvous critical path (release-add delayed every step,
//      convoy amplifies -- same mechanism as R26). This round isolates
//      FMA-select: a += fma(wd, dd==k ? 1.0 : 0.0, a); 1.0/0.0 share a zero
//      low word -> cmp + 1 cndmask_b32 + v_fma_f64 per slot (was cmp +
//      cndmask_b64 + add_f64). Bit-exact: fma(w,1,a)=round(a+w);
//      fma(w,0,a)=a (+0-safe, ring slots never -0). ACC order unchanged.
// R24: RELAXED spin (acquire's per-poll buffer_inv nuked XCD L2; +7.5%).
// R17/R18: 256x1024, 2 threads/neuron (halves split slist/ilist; f64 partials
//      combined via LDS). R15 gate: z_{t-1} delivered iff t>=2.
// ---- d_ws layout (~28.3 MB; 34.5 MB verified safe) ----
#define OFF_WRT  0UL          // f32 W_rT [n][m] (exact; 0 where d==0) 16,777,216
#define OFF_DP2  16777216UL   // u32 dP2[n][m/16] 2-bit delays         1,048,576
#define OFF_WIT  17825792UL   // f32 W_i^T [i][m]                      4,194,304
#define OFF_WOT  22020096UL   // f32 W_o^T [n][o]                      1,048,576
#define OFF_MASK 23068672UL   // u32 masks [t*64+b][64]                4,096,000
#define OFF_G    27164672UL   // f64 g[b][n]                           1,048,576
#define OFF_CNT  28213248UL   // u32 cnt[t*64+b]                          64,000

__device__ __forceinline__ int decode_delay(int v) {
    if (v >= 0 && v <= 4) return v;
    const float f = __int_as_float(v);
    if (f >= 0.5f && f <= 4.5f) return (int)(f + 0.5f);
    return 0;
}
__device__ __forceinline__ int delay_like(int v) {
    if (v >= 0 && v <= 4) return 1;
    const float f = __int_as_float(v);
    return (f >= 0.5f && f <= 4.5f) ? 1 : 0;
}
__device__ __forceinline__ unsigned lane_rank(unsigned long long m) {
    unsigned r = __builtin_amdgcn_mbcnt_lo((unsigned)m, 0u);
    return __builtin_amdgcn_mbcnt_hi((unsigned)(m >> 32), r);
}

__global__ __launch_bounds__(256) void k_prep(
    const void* __restrict__ c4A, const void* __restrict__ c4B,
    const float* __restrict__ Wi, const float* __restrict__ Wo,
    float* __restrict__ WrT, unsigned* __restrict__ dP2,
    float* __restrict__ WiT, float* __restrict__ WoT)
{
    const int* iA = (const int*)c4A;
    const int* iB = (const int*)c4B;
    int cntA = 0, cntB = 0;
    for (int j = 0; j < 64; ++j) { cntA += delay_like(iA[j]); cntB += delay_like(iB[j]); }
    const int*   dl = (cntA >= cntB) ? iA : iB;
    const float* Wr = (cntA >= cntB) ? (const float*)c4B : (const float*)c4A;

    const int idx = blockIdx.x * 256 + threadIdx.x;
    if (idx < NREC * NREC) {
        const int n = idx >> 11, m = idx & 2047;
        const int d = decode_delay(dl[idx]);
        const float w = Wr[(size_t)m * NREC + n];        // W_rT[n][m] = W_r[m][n]
        WrT[idx] = (d == 0) ? 0.0f : w;                  // exact bits where it matters
        if ((m & 15) == 0) {                             // pack 16 delays -> 1 u32
            unsigned pw = 0;
            for (int j = 0; j < 16; ++j) {
                const int dj = decode_delay(dl[idx + j]);
                const unsigned e = (dj == 0) ? 0u : (unsigned)(dj - 1);
                pw |= e << (2 * j);
            }
            dP2[idx >> 4] = pw;
        }
    }
    if (idx < NIN * NREC) {
        const int i = idx >> 11, m = idx & 2047;
        WiT[idx] = Wi[(size_t)m * NIN + i];              // W_iT[i][m]
    }
    if (idx < NREC * NOUT) {
        const int n = idx >> 7, o = idx & 127;
        WoT[idx] = Wo[(size_t)o * NREC + n];             // W_oT[n][o]
    }
}

// per-event accumulate via FMA-select (R29): fma(wd, sel01, a), sel01 in
// {1.0, 0.0} (shared zero low word -> 1 cndmask_b32 + 1 v_fma_f64 per slot).
// Bit-exact vs add: fma(w,1,a)=round(a+w); fma(w,0,a)=a (+0-safe).
#define ACCEV(wf, ee) { const int dd = (int)(((ee) >> sh) & 3u);                \
    const double wd = (double)(wf);                                             \
    a0 = __builtin_fma(wd, (dd == 0) ? 1.0 : 0.0, a0);                          \
    a1 = __builtin_fma(wd, (dd == 1) ? 1.0 : 0.0, a1);                          \
    a2 = __builtin_fma(wd, (dd == 2) ? 1.0 : 0.0, a2);                          \
    a3 = __builtin_fma(wd, (dd == 3) ? 1.0 : 0.0, a3); }

// 256 blocks x 1024 threads. Block (b,q) owns neuron cols [512q,512q+512) of
// batch b; 2 threads/neuron (half=tid>>9). Per-step phase order:
//   [split input gather(t) -- overlaps z_{t-1} propagation] -> relaxed spin
//   cnt[t-1]==4 -> B3 -> wave0: masks+scan+slist -> B4 -> split scatter
//   (t>=2) -> combine partial a0/cin via LDS -> LIF on half0 -> publish z_t
//   -> release cnt[t].
// Residency: 16 waves/block; all 256 blocks co-resident -> spin can't deadlock.
__global__ __launch_bounds__(1024) void k_main(
    const float* __restrict__ x,
    const float* __restrict__ WrT,
    const unsigned* __restrict__ dP2,
    const float* __restrict__ WiT,
    const float* __restrict__ Br,
    const float* __restrict__ tau_rec, const float* __restrict__ tau_out,
    const float* __restrict__ thr_rec,
    unsigned* __restrict__ spikeMask, unsigned* __restrict__ cnt,
    double* __restrict__ g)
{
    __shared__ int icnt[8];
    __shared__ __align__(16) unsigned short ilist[NIN];
    __shared__ __align__(16) unsigned short slist[NREC];
    __shared__ int stot_s;
    __shared__ double aEx[512];
    __shared__ double cEx[512];

    const int gid = blockIdx.x;
    const int r8  = gid & 7, kk0 = gid >> 3;
    const int q   = r8 >> 1;
    const int b   = kk0 * 2 + (r8 & 1);
    const int tid  = threadIdx.x;
    const int half = tid >> 9;               // 0: front events + LIF; 1: back events
    const int u    = tid & 511;              // neuron index within block slice
    const int w    = tid >> 6;               // wave 0..15
    const int lane = tid & 63;
    const int col  = q * 512 + u;            // my neuron (global id)
    const unsigned colu = (unsigned)col;
    const unsigned c4i  = colu >> 4;         // dP2 word column (per-thread const)
    const int sh        = (col & 15) * 2;    // dP2 bit shift   (per-thread const)

    const double rec_c = exp(-0.01 / (double)tau_rec[0]);
    const double out_c = exp(-0.01 / (double)tau_out[0]);
    const double thr   = (double)thr_rec[0];
    const double br    = (double)Br[col];
    double mem = 0.0, gacc = 0.0;
    double a0 = 0.0, a1 = 0.0, a2 = 0.0, a3 = 0.0;   // per-half register delay ring

    const float* xb = x + (size_t)b * NIN * TT;      // x[b][i][t]
    const float* Wc = WiT + col;                     // per-thread input column base
    float xv = (half == 0) ? xb[(size_t)u * TT] : 0.f;   // u < 512 == NIN

    for (int t = 0; t < TT; ++t) {
        // ---- input ballot (half0 waves) + split gather (both halves) ----
        const bool ihit = (xv != 0.f);
        const unsigned long long im = __ballot(ihit);
        if (w < 8 && lane == 0) icnt[w] = __popcll(im);
        float xvn = 0.f;
        if (half == 0 && t + 1 < TT) xvn = xb[(size_t)u * TT + (t + 1)];
        __syncthreads();                               // B1: icnt ready
        int ioffw = 0, itot = 0;
#pragma unroll
        for (int j = 0; j < 8; ++j) { const int c = icnt[j]; if (j < w) ioffw += c; itot += c; }
        if (ihit) ilist[ioffw + lane_rank(im)] = (unsigned short)u;
        __syncthreads();                               // B2: ilist ready
        int iHalf = ((itot >> 1) + 7) & ~7; if (iHalf > itot) iHalf = itot;  // 8-aligned split
        const int ikb = half ? iHalf : 0;
        const int ike = half ? itot  : iHalf;
        double cin = 0.0;
        {
            int k = ikb;
            for (; k + 8 <= ike; k += 8) {
                const uint4 sv = *reinterpret_cast<const uint4*>(&ilist[k]);
                const float v0 = Wc[(sv.x & 0xffffu) << 11];
                const float v1 = Wc[(sv.x >> 16)     << 11];
                const float v2 = Wc[(sv.y & 0xffffu) << 11];
                const float v3 = Wc[(sv.y >> 16)     << 11];
                const float v4 = Wc[(sv.z & 0xffffu) << 11];
                const float v5 = Wc[(sv.z >> 16)     << 11];
                const float v6 = Wc[(sv.w & 0xffffu) << 11];
                const float v7 = Wc[(sv.w >> 16)     << 11];
                cin += (double)v0; cin += (double)v1; cin += (double)v2; cin += (double)v3;
                cin += (double)v4; cin += (double)v5; cin += (double)v6; cin += (double)v7;
            }
            for (; k < ike; ++k) cin += (double)Wc[(unsigned)ilist[k] << 11];
        }
        xv = xvn;

        // ---- wait for siblings' z_{t-1}; deliver only if t-1 > 0 (R15 gate) ----
        if (t >= 2) {
            const unsigned* gmp = spikeMask + (size_t)((t - 1) * BB + b) * 64;
            if (tid == 0) {
                // RELAXED poll (R24): acquire's per-poll buffer_inv would nuke
                // the XCD L2 weight slice. Ordering: producers drain sc1 mask
                // stores at their B5 before the release-add; our reads are
                // relaxed sc1 loads after the spin + B3.
                while (__hip_atomic_load(&cnt[(t - 1) * BB + b],
                                         __ATOMIC_RELAXED, __HIP_MEMORY_SCOPE_AGENT) < 4u)
                    __builtin_amdgcn_s_sleep(1);
            }
            __syncthreads();                           // B3: z_{t-1} all published
            if (tid < 64) {                            // wave 0: scan + emit slist
                const unsigned wv = __hip_atomic_load(&gmp[tid],
                                        __ATOMIC_RELAXED, __HIP_MEMORY_SCOPE_AGENT);
                const int zc = __popc(wv);
                int inc = zc;
#pragma unroll
                for (int s = 1; s < 64; s <<= 1) {
                    const int up = __shfl_up(inc, s, 64);
                    if (lane >= s) inc += up;
                }
                int off = inc - zc;                    // exclusive prefix
                if (lane == 63) stot_s = inc;
                unsigned bits = wv;
                while (bits) {
                    const int bp = __ffs(bits) - 1;
                    bits &= bits - 1;
                    slist[off++] = (unsigned short)(tid * 32 + bp);
                }
            }
            __syncthreads();                           // B4: slist/stot ready
            const int stot = stot_s;
            int sHalf = ((stot >> 1) + 7) & ~7; if (sHalf > stot) sHalf = stot; // 8-aligned
            const int kb = half ? sHalf : 0;
            const int ke = half ? stot  : sHalf;
            int k = kb;
            for (; k + 8 <= ke; k += 8) {
                const uint4 sv = *reinterpret_cast<const uint4*>(&slist[k]);
                const unsigned n0 = sv.x & 0xffffu, n1 = sv.x >> 16;
                const unsigned n2 = sv.y & 0xffffu, n3 = sv.y >> 16;
                const unsigned n4 = sv.z & 0xffffu, n5 = sv.z >> 16;
                const unsigned n6 = sv.w & 0xffffu, n7 = sv.w >> 16;
                const float w0 = WrT[(n0 << 11) | colu]; const unsigned e0 = dP2[(n0 << 7) | c4i];
                const float w1 = WrT[(n1 << 11) | colu]; const unsigned e1 = dP2[(n1 << 7) | c4i];
                const float w2 = WrT[(n2 << 11) | colu]; const unsigned e2 = dP2[(n2 << 7) | c4i];
                const float w3 = WrT[(n3 << 11) | colu]; const unsigned e3 = dP2[(n3 << 7) | c4i];
                const float w4 = WrT[(n4 << 11) | colu]; const unsigned e4 = dP2[(n4 << 7) | c4i];
                const float w5 = WrT[(n5 << 11) | colu]; const unsigned e5 = dP2[(n5 << 7) | c4i];
                const float w6 = WrT[(n6 << 11) | colu]; const unsigned e6 = dP2[(n6 << 7) | c4i];
                const float w7 = WrT[(n7 << 11) | colu]; const unsigned e7 = dP2[(n7 << 7) | c4i];
                ACCEV(w0, e0) ACCEV(w1, e1) ACCEV(w2, e2) ACCEV(w3, e3)
                ACCEV(w4, e4) ACCEV(w5, e5) ACCEV(w6, e6) ACCEV(w7, e7)
            }
            for (; k < ke; ++k) {
                const unsigned n0 = (unsigned)slist[k];
                const float w0 = WrT[(n0 << 11) | colu];
                const unsigned e0 = dP2[(n0 << 7) | c4i];
                ACCEV(w0, e0)
            }
        }

        // ---- combine halves (slot 0 + cin only), LIF on half0 ----
        if (half) { aEx[u] = a0; cEx[u] = cin; }
        __syncthreads();                               // B6: partials ready
        bool z = false;
        if (half == 0) {
            const double cur = (a0 + aEx[u]) + (cin + cEx[u]) + br;
            mem = mem * rec_c + cur;
            z = (mem - thr) > 0.0;
            if (z) mem -= thr;
            gacc = gacc * out_c + (z ? 1.0 : 0.0);
        }
        a0 = a1; a1 = a2; a2 = a3; a3 = 0.0;           // both halves rotate

        // ---- publish z_t from half0 wave ballots; release counter ----
        const unsigned long long mz = __ballot(z);
        unsigned* gm = spikeMask + (size_t)(t * BB + b) * 64;
        if (w < 8) {
            if (lane == 0)
                __hip_atomic_store(&gm[q * 16 + 2 * w], (unsigned)(mz & 0xFFFFFFFFu),
                                   __ATOMIC_RELAXED, __HIP_MEMORY_SCOPE_AGENT);
            if (lane == 32)
                __hip_atomic_store(&gm[q * 16 + 2 * w + 1], (unsigned)(mz >> 32),
                                   __ATOMIC_RELAXED, __HIP_MEMORY_SCOPE_AGENT);
        }
        __syncthreads();                               // B5: stores drained -> visible
        if (tid == 0)
            __hip_atomic_fetch_add(&cnt[t * BB + b], 1u,
                                   __ATOMIC_RELEASE, __HIP_MEMORY_SCOPE_AGENT);
    }

    if (half == 0) g[(size_t)b * NREC + col] = gacc;
}

__global__ __launch_bounds__(256) void k_memout(
    const double* __restrict__ g, const float* __restrict__ WoT,
    const float* __restrict__ Bo, const float* __restrict__ tau_out,
    float* __restrict__ mout)
{
    __shared__ double gs[NREC];
    const int b = blockIdx.x, tid = threadIdx.x;
#pragma unroll
    for (int k = 0; k < 8; ++k)
        gs[tid + 256 * k] = g[(size_t)b * NREC + tid + 256 * k];
    const double c = exp(-0.01 / (double)tau_out[0]);
    double S = 0.0;
    for (int t = 0; t < TT; ++t) S = S * c + 1.0;
    __syncthreads();
    if (tid < NOUT) {
        double a = 0.0;
        for (int n = 0; n < NREC; ++n)
            a += gs[n] * (double)WoT[n * NOUT + tid];
        a += (double)Bo[tid] * S;
        mout[(size_t)b * NOUT + tid] = (float)a;
    }
}

__global__ __launch_bounds__(256) void k_expand(
    const unsigned* __restrict__ spikeMask, float* __restrict__ zout)
{
    const int bid = blockIdx.x;
    const int b = bid >> 6, gw = bid & 63;
    const int t = threadIdx.x;
    if (t >= TT) return;
    const unsigned v = spikeMask[((size_t)(t * BB + b)) * 64 + gw];
    for (int j = 0; j < 32; ++j) {
        const int n = gw * 32 + j;
        zout[((size_t)b * NREC + n) * TT + t] = ((v >> j) & 1u) ? 1.0f : 0.0f;
    }
}

extern "C" void kernel_launch(void* const* d_in, const int* in_sizes, int n_in,
                              void* d_out, int out_size, void* d_ws, size_t ws_size,
                              hipStream_t stream) {
    const float *x = nullptr, *Wi = nullptr, *Wo = nullptr, *Br = nullptr, *Bo = nullptr;
    const void* c4[2] = {nullptr, nullptr};
    const float* sc[3] = {nullptr, nullptr, nullptr};
    int n4 = 0, nsc = 0;
    for (int i = 0; i < n_in; ++i) {
        switch (in_sizes[i]) {
            case 8192000: x  = (const float*)d_in[i]; break;
            case 1048576: Wi = (const float*)d_in[i]; break;
            case 262144:  Wo = (const float*)d_in[i]; break;
            case 2048:    Br = (const float*)d_in[i]; break;
            case 128:     Bo = (const float*)d_in[i]; break;
            case 4194304: if (n4 < 2)  c4[n4++]  = d_in[i]; break;
            case 1:       if (nsc < 3) sc[nsc++] = (const float*)d_in[i]; break;
            default: break;
        }
    }
    if (!x || !Wi || !Wo || !Br || !Bo || n4 < 2 || nsc < 3) {
        x  = (const float*)d_in[0];
        c4[0] = d_in[1];
        Wi = (const float*)d_in[2];
        c4[1] = d_in[3];
        Wo = (const float*)d_in[4];
        Br = (const float*)d_in[5];
        Bo = (const float*)d_in[6];
        sc[0] = (const float*)d_in[7];
        sc[1] = (const float*)d_in[8];
        sc[2] = (const float*)d_in[9];
    }
    const float* taur = sc[0];
    const float* tauo = sc[1];
    const float* thr  = sc[2];

    float* out = (float*)d_out;
    char* ws = (char*)d_ws;
    float*          WrT  = (float*)(ws + OFF_WRT);
    unsigned*       dP2  = (unsigned*)(ws + OFF_DP2);
    float*          WiT  = (float*)(ws + OFF_WIT);
    float*          WoT  = (float*)(ws + OFF_WOT);
    unsigned*       mask = (unsigned*)(ws + OFF_MASK);
    double*         g    = (double*)(ws + OFF_G);
    unsigned*       cnt  = (unsigned*)(ws + OFF_CNT);

    hipMemsetAsync(cnt, 0, (size_t)TT * BB * sizeof(unsigned), stream);
    hipLaunchKernelGGL(k_prep, dim3((NREC * NREC + 255) / 256), dim3(256), 0, stream,
                       c4[0], c4[1], Wi, Wo, WrT, dP2, WiT, WoT);
    hipLaunchKernelGGL(k_main, dim3(256), dim3(1024), 0, stream,
                       x, WrT, dP2, WiT, Br, taur, tauo, thr, mask, cnt, g);
    hipLaunchKernelGGL(k_memout, dim3(BB), dim3(256), 0, stream,
                       g, WoT, Bo, tauo, out);
    hipLaunchKernelGGL(k_expand, dim3(BB * 64), dim3(256), 0, stream,
                       mask, out + 8192);
}